// Round 1
// baseline (363.745 us; speedup 1.0000x reference)
//
#include <hip/hip_runtime.h>

// Problem constants (setup_inputs is fixed): B=32, T_in=512, D=512, L=2048.
// x: (B,T,D) fp32; durations: (B,T) fp32; outputs: aligned (B,L,D) fp32 then
// attn (B,T,L) fp32, concatenated flat in d_out.

static constexpr int Bc = 32;
static constexpr int Tc = 512;
static constexpr int Dc = 512;
static constexpr int Lc = 2048;
static constexpr float SIGMA = 0.2f;
// exponent cutoff: terms with 0.2*(s^2 - smin^2) > 40 are < e^-40 of the max
// term (denom >= 1 after max-subtraction) -> zero within any fp32 tolerance.
static constexpr float CUT = 40.0f / SIGMA; // s^2 slack = 200

// Kernel 1: starts[b][t] = exclusive cumsum of durations along t.
__global__ void cumsum_starts(const float* __restrict__ dur,
                              float* __restrict__ starts) {
  const int b = blockIdx.x;
  const int t = threadIdx.x; // blockDim.x == Tc
  __shared__ float buf[Tc];
  float d = dur[(size_t)b * Tc + t];
  float v = d;
  buf[t] = v;
  __syncthreads();
  for (int off = 1; off < Tc; off <<= 1) {
    float add = (t >= off) ? buf[t - off] : 0.0f;
    __syncthreads();
    v += add;
    buf[t] = v;
    __syncthreads();
  }
  starts[(size_t)b * Tc + t] = v - d; // exclusive scan
}

// Kernel 2: one block (128 threads = 2 waves) per (b,l).
// Band softmax + gather-FMA into aligned; scatter band attn values.
__global__ void __launch_bounds__(128)
band_softmax_align(const float* __restrict__ x,
                   const float* __restrict__ starts,
                   float* __restrict__ aligned,
                   float* __restrict__ attn) {
  const int bl = blockIdx.x;
  const int b = bl >> 11;        // / Lc
  const int l = bl & (Lc - 1);   // % Lc
  const float fl = (float)l;
  const float* __restrict__ sb = starts + (size_t)b * Tc;

  // p = first index with sb[p] > fl (starts are strictly increasing)
  int lo = 0, hi = Tc;
  while (lo < hi) { int mid = (lo + hi) >> 1; if (sb[mid] <= fl) lo = mid + 1; else hi = mid; }
  const int p = lo;

  // global min |fl - start[t]| is at p-1 or p
  float smin = 1e30f;
  if (p > 0)  smin = fminf(smin, fl - sb[p - 1]);
  if (p < Tc) smin = fminf(smin, sb[p] - fl);
  const float smax = sqrtf(smin * smin + CUT);

  // band = tokens with start in [fl - smax, fl + smax] (contiguous, monotone)
  const float loV = fl - smax, hiV = fl + smax;
  lo = 0; hi = p;
  while (lo < hi) { int mid = (lo + hi) >> 1; if (sb[mid] < loV) lo = mid + 1; else hi = mid; }
  const int t0 = lo;
  lo = p; hi = Tc;
  while (lo < hi) { int mid = (lo + hi) >> 1; if (sb[mid] <= hiV) lo = mid + 1; else hi = mid; }
  const int t1 = lo; // band nonempty: nearest token is inside by construction

  __shared__ float wbuf[Tc];
  const float m = SIGMA * smin * smin; // subtracted max exponent (negated)
  const int tid = threadIdx.x;         // 0..127, covers D=512 as float4
  const float4* __restrict__ xb = (const float4*)(x + (size_t)b * Tc * Dc);

  float denom = 0.0f;
  float4 acc = make_float4(0.f, 0.f, 0.f, 0.f);
  for (int t = t0; t < t1; ++t) {
    const float s = fl - sb[t];
    const float w = __expf(m - SIGMA * s * s); // in (0,1], max term = 1
    if (tid == 0) wbuf[t - t0] = w;
    denom += w;
    const float4 xv = xb[(size_t)t * (Dc / 4) + tid];
    acc.x += w * xv.x; acc.y += w * xv.y; acc.z += w * xv.z; acc.w += w * xv.w;
  }
  const float inv = 1.0f / denom;
  acc.x *= inv; acc.y *= inv; acc.z *= inv; acc.w *= inv;

  float4* __restrict__ ab = (float4*)(aligned + ((size_t)b * Lc + l) * Dc);
  ab[tid] = acc;

  __syncthreads(); // wbuf written by lane 0 of wave 0, read by all
  for (int i = tid; i < t1 - t0; i += 128) {
    attn[((size_t)b * Tc + (t0 + i)) * Lc + l] = wbuf[i] * inv;
  }
}

extern "C" void kernel_launch(void* const* d_in, const int* in_sizes, int n_in,
                              void* d_out, int out_size, void* d_ws, size_t ws_size,
                              hipStream_t stream) {
  const float* x   = (const float*)d_in[0];
  const float* dur = (const float*)d_in[1];

  float* aligned = (float*)d_out;                       // B*L*D floats
  float* attn    = (float*)d_out + (size_t)Bc * Lc * Dc; // B*T*L floats
  float* starts  = (float*)d_ws;                         // B*T floats

  // attn is banded-sparse: zero-fill, then scatter significant values.
  hipMemsetAsync(attn, 0, (size_t)Bc * Tc * Lc * sizeof(float), stream);

  cumsum_starts<<<Bc, Tc, 0, stream>>>(dur, starts);
  band_softmax_align<<<Bc * Lc, 128, 0, stream>>>(x, starts, aligned, attn);
}